// Round 4
// baseline (176.585 us; speedup 1.0000x reference)
//
#include <hip/hip_runtime.h>
#include <math.h>

typedef __bf16 bf16x8 __attribute__((ext_vector_type(8)));
typedef __bf16 bf16x4 __attribute__((ext_vector_type(4)));
typedef float f32x4 __attribute__((ext_vector_type(4)));

#define PI_D 3.14159265358979323846

// ---------------------------------------------------------------------------
// Prep: pack weights into MFMA-fragment-ordered bf16 (A-operand layout:
// within-tile idx = lane&15 on the output dim, k = (lane>>4)*8 + j).
// Packed flat: [((tile*KS + ks)*64 + l)*8 + j] -> wave reads contiguous 1KB.
// ---------------------------------------------------------------------------
__global__ void prep_kernel(const float* __restrict__ dir_W,
                            const float* __restrict__ proj1_W,
                            const float* __restrict__ proj2_W,
                            const float* __restrict__ gbf_stds,
                            __bf16* __restrict__ dirP, __bf16* __restrict__ p1P,
                            __bf16* __restrict__ p2P,
                            float* __restrict__ f_az, float* __restrict__ f_po,
                            float* __restrict__ inv_std, float* __restrict__ coef) {
  int tid = threadIdx.x + blockIdx.x * blockDim.x;
  int nth = gridDim.x * blockDim.x;
  // dir_W (256 x 256): 16 d-tiles, 8 ksteps
  for (int o = tid; o < 256 * 256; o += nth) {
    int j = o & 7, l = (o >> 3) & 63, ks = (o >> 9) & 7, nt = o >> 12;
    int d = nt * 16 + (l & 15);
    int s = ks * 32 + (l >> 4) * 8 + j;
    dirP[o] = (__bf16)dir_W[s * 256 + d];
  }
  // proj1_W (128 x 128): 8 ko-tiles, 4 ksteps
  for (int o = tid; o < 128 * 128; o += nth) {
    int j = o & 7, l = (o >> 3) & 63, ks = (o >> 9) & 3, nt = o >> 11;
    int ko = nt * 16 + (l & 15);
    int ki = ks * 32 + (l >> 4) * 8 + j;
    p1P[o] = (__bf16)proj1_W[ki * 128 + ko];
  }
  // proj2_W (128 x 256): 16 d-tiles, 4 ksteps
  for (int o = tid; o < 128 * 256; o += nth) {
    int j = o & 7, l = (o >> 3) & 63, ks = (o >> 9) & 3, nt = o >> 11;
    int d = nt * 16 + (l & 15);
    int k = ks * 32 + (l >> 4) * 8 + j;
    p2P[o] = (__bf16)proj2_W[k * 256 + d];
  }
  if (blockIdx.x == 0 && threadIdx.x < 64) {
    int q = threadIdx.x;
    double l0 = log(2.0 * 1e-4);
    double l1a = log(2.0 * 2.0 * PI_D);
    double l1p = log(2.0 * PI_D);
    double ta = l0 + (l1a - l0) * (double)q / 63.0;
    double tp = l0 + (l1p - l0) * (double)q / 63.0;
    f_az[q] = (float)(2.0 * PI_D / exp(ta));
    f_po[q] = (float)(2.0 * PI_D / exp(tp));
  }
  if (blockIdx.x == 1 && threadIdx.x < 128) {
    int k = threadIdx.x;
    float sd = fabsf(gbf_stds[k]) + 0.01f;
    inv_std[k] = 1.0f / sd;
    coef[k] = (float)(1.0 / (sqrt(2.0 * 3.14159) * (double)sd));
  }
}

// ---------------------------------------------------------------------------
// Node features: node = emb_z[z] + elec + mult_W[1] + charge_W[0]
// ---------------------------------------------------------------------------
__global__ void node_kernel(const int* __restrict__ an, const float* __restrict__ emb_z,
                            const float* __restrict__ ec, const float* __restrict__ cW,
                            const float* __restrict__ cb, const float* __restrict__ mult_W,
                            const float* __restrict__ charge_W, float* __restrict__ out_node) {
  int bi = blockIdx.x;  // b*256 + i
  int b = bi >> 8, i = bi & 255;
  int d = threadIdx.x;
  int z = (i == 0) ? 101 : an[b * 255 + i - 1];
  float elec = 0.0f;
  if (i != 0) {
    for (int f = 0; f < 20; ++f) elec += ec[z * 20 + f] * cW[f * 256 + d];
    elec += cb[d];
  }
  float v = emb_z[z * 256 + d] + elec + mult_W[256 + d] + charge_W[d];
  out_node[(size_t)bi * 256 + d] = v;
}

// ---------------------------------------------------------------------------
// Dir kernel: sinusoids -> LDS -> GEMM [256 d] x [256 k] -> store.
// Stores only at kernel end, no barrier after them.
// ---------------------------------------------------------------------------
__global__ __launch_bounds__(256, 4) void dir_kernel(
    const float* __restrict__ positions, const float* __restrict__ dir_b,
    const __bf16* __restrict__ dirP, const float* __restrict__ f_az,
    const float* __restrict__ f_po, float* __restrict__ out_dir) {
  __shared__ __align__(16) __bf16 sin_t[64 * 264];
  __shared__ float s_az[64], s_po[64];

  const int tid = threadIdx.x;
  const int bid = blockIdx.x;
  const int jt = bid & 3;
  const int i = (bid >> 2) & 255;
  const int b = bid >> 10;
  const int j0 = jt * 64;
  const long pairbase = ((long)(b * 256 + i)) * 256 + j0;
  const int lane = tid & 63, wv = tid >> 6;
  const int lr = lane & 15, kb = lane >> 4;

  // ---- scalars ----
  if (tid < 64) {
    int p = tid, j = j0 + p;
    float pxi = 0.f, pyi = 0.f, pzi = 0.f, pxj = 0.f, pyj = 0.f, pzj = 0.f;
    if (i != 0) { const float* q = positions + ((size_t)b * 255 + (i - 1)) * 3; pxi = q[0]; pyi = q[1]; pzi = q[2]; }
    if (j != 0) { const float* q = positions + ((size_t)b * 255 + (j - 1)) * 3; pxj = q[0]; pyj = q[1]; pzj = q[2]; }
    float dx = pxj - pxi, dy = pyj - pyi, dz = pzj - pzi;
    float sq = dx * dx + dy * dy + dz * dz;
    float dist = sqrtf(sq + 1e-12f);
    float inv = 1.0f / (dist + 1e-5f);
    float ndx = dx * inv, ndy = dy * inv, ndz = dz * inv;
    bool diag = (i == j);
    float xs = diag ? 1.0f : ndx;
    float ys = diag ? 0.0f : ndy;
    s_az[p] = atan2f(ys, xs);
    float cz = fminf(fmaxf(ndz, -1.0f + 1e-6f), 1.0f - 1e-6f);
    s_po[p] = acosf(cz);
  }
  __syncthreads();

  // ---- stage sinusoids: row p pitch 264: [sin_az 64|cos_az 64|sin_po 64|cos_po 64]
  for (int it = 0; it < 4; ++it) {
    int job = tid + it * 256;  // 64 p * 16 groups
    int p = job >> 4, g = job & 15;
    bool az = g < 8;
    int q0 = (g & 7) * 8;
    float ang = az ? s_az[p] : s_po[p];
    const float* ft = az ? f_az : f_po;
    bf16x8 sv, cv;
#pragma unroll
    for (int t = 0; t < 8; ++t) {
      float ph = ang * ft[q0 + t];  // f32 product, same as reference
      double r = (double)ph * 0.15915494309189535;  // /(2*pi) -> revolutions
      double fr = r - rint(r);                      // exact reduction
      float frf = (float)fr;
      sv[t] = (__bf16)__builtin_amdgcn_sinf(frf);   // sin(2*pi*x)
      cv[t] = (__bf16)__builtin_amdgcn_cosf(frf);
    }
    int base = p * 264 + (az ? 0 : 128) + q0;
    *(bf16x8*)(sin_t + base) = sv;
    *(bf16x8*)(sin_t + base + 64) = cv;
  }
  __syncthreads();

  // ---- GEMM: A = dir_W fragments (d rows), B = sinusoid fragments (pairs)
  f32x4 acc[4][4];
#pragma unroll
  for (int mtl = 0; mtl < 4; ++mtl)
#pragma unroll
    for (int np = 0; np < 4; ++np) acc[mtl][np] = (f32x4){0.f, 0.f, 0.f, 0.f};
#pragma unroll
  for (int ks = 0; ks < 8; ++ks) {
    bf16x8 bfr[4];
#pragma unroll
    for (int np = 0; np < 4; ++np)
      bfr[np] = *(const bf16x8*)(sin_t + (np * 16 + lr) * 264 + ks * 32 + kb * 8);
#pragma unroll
    for (int mtl = 0; mtl < 4; ++mtl) {
      int mtile = mtl * 4 + wv;
      bf16x8 af = *(const bf16x8*)(dirP + (((size_t)mtile * 8 + ks) * 64 + lane) * 8);
#pragma unroll
      for (int np = 0; np < 4; ++np)
        acc[mtl][np] = __builtin_amdgcn_mfma_f32_16x16x32_bf16(af, bfr[np], acc[mtl][np], 0, 0, 0);
    }
  }
  // ---- epilogue: f32x4 stores, nothing after ----
#pragma unroll
  for (int mtl = 0; mtl < 4; ++mtl) {
    int dcol0 = (mtl * 4 + wv) * 16 + kb * 4;
    f32x4 bias = *(const f32x4*)(dir_b + dcol0);
#pragma unroll
    for (int np = 0; np < 4; ++np) {
      f32x4 v = acc[mtl][np] + bias;
      *(f32x4*)(out_dir + (pairbase + np * 16 + lr) * 256 + dcol0) = v;
    }
  }
}

// ---------------------------------------------------------------------------
// GBF kernel: gauss -> proj1 -> GELU -> proj2 -> store. Stores only at end.
// ---------------------------------------------------------------------------
__global__ __launch_bounds__(256, 4) void gbf_kernel(
    const float* __restrict__ positions, const int* __restrict__ atomic_numbers,
    const float* __restrict__ gbf_means, const float* __restrict__ gbf_mul,
    const float* __restrict__ gbf_bias, const float* __restrict__ proj1_b,
    const float* __restrict__ proj2_b, const __bf16* __restrict__ p1P,
    const __bf16* __restrict__ p2P, const float* __restrict__ inv_stdv,
    const float* __restrict__ coefv, float* __restrict__ out_gbf) {
  __shared__ __align__(16) __bf16 g_t[64 * 136];
  __shared__ __align__(16) __bf16 h_t[64 * 136];
  __shared__ float s_gx[64];

  const int tid = threadIdx.x;
  const int bid = blockIdx.x;
  const int jt = bid & 3;
  const int i = (bid >> 2) & 255;
  const int b = bid >> 10;
  const int j0 = jt * 64;
  const long pairbase = ((long)(b * 256 + i)) * 256 + j0;
  const int lane = tid & 63, wv = tid >> 6;
  const int lr = lane & 15, kb = lane >> 4;

  // ---- scalars ----
  if (tid < 64) {
    int p = tid, j = j0 + p;
    float pxi = 0.f, pyi = 0.f, pzi = 0.f, pxj = 0.f, pyj = 0.f, pzj = 0.f;
    if (i != 0) { const float* q = positions + ((size_t)b * 255 + (i - 1)) * 3; pxi = q[0]; pyi = q[1]; pzi = q[2]; }
    if (j != 0) { const float* q = positions + ((size_t)b * 255 + (j - 1)) * 3; pxj = q[0]; pyj = q[1]; pzj = q[2]; }
    float dx = pxj - pxi, dy = pyj - pyi, dz = pzj - pzi;
    float sq = dx * dx + dy * dy + dz * dz;
    float dist = sqrtf(sq + 1e-12f);
    int zi = (i == 0) ? 101 : atomic_numbers[b * 255 + i - 1];
    int zj = ((j == 0) ? 101 : atomic_numbers[b * 255 + j - 1]) + 128;
    float mul = gbf_mul[zi] + gbf_mul[zj];
    float bia = gbf_bias[zi] + gbf_bias[zj];
    s_gx[p] = mul * dist + bia;
  }
  __syncthreads();

  // ---- gauss stage ----
#pragma unroll
  for (int it = 0; it < 4; ++it) {
    int job = tid + it * 256;  // 64 p * 16 groups
    int p = job >> 4, g = job & 15;
    int k0 = g * 8;
    float gx = s_gx[p];
    bf16x8 gv;
#pragma unroll
    for (int t = 0; t < 8; ++t) {
      int k = k0 + t;
      float x = (gx - gbf_means[k]) * inv_stdv[k];
      gv[t] = (__bf16)(exp2f(-0.72134752044448170f * x * x) * coefv[k]);
    }
    *(bf16x8*)(g_t + p * 136 + k0) = gv;
  }
  __syncthreads();

  // ---- proj1: [128 ko] x [128 k] @ gauss^T ----
  f32x4 acc1[2][4];
#pragma unroll
  for (int mtl = 0; mtl < 2; ++mtl)
#pragma unroll
    for (int np = 0; np < 4; ++np) acc1[mtl][np] = (f32x4){0.f, 0.f, 0.f, 0.f};
#pragma unroll
  for (int ksl = 0; ksl < 4; ++ksl) {
    bf16x8 bfr[4];
#pragma unroll
    for (int np = 0; np < 4; ++np)
      bfr[np] = *(const bf16x8*)(g_t + (np * 16 + lr) * 136 + ksl * 32 + kb * 8);
#pragma unroll
    for (int mtl = 0; mtl < 2; ++mtl) {
      int mtile = mtl * 4 + wv;  // 0..7
      bf16x8 af = *(const bf16x8*)(p1P + (((size_t)mtile * 4 + ksl) * 64 + lane) * 8);
#pragma unroll
      for (int np = 0; np < 4; ++np)
        acc1[mtl][np] = __builtin_amdgcn_mfma_f32_16x16x32_bf16(af, bfr[np], acc1[mtl][np], 0, 0, 0);
    }
  }

  // ---- GELU -> h_t (disjoint from g_t; no barrier needed before writes) ----
#pragma unroll
  for (int mtl = 0; mtl < 2; ++mtl) {
    int ko0 = (mtl * 4 + wv) * 16 + kb * 4;
    f32x4 pb = *(const f32x4*)(proj1_b + ko0);
#pragma unroll
    for (int np = 0; np < 4; ++np) {
      f32x4 hv = acc1[mtl][np] + pb;
      bf16x4 hb;
#pragma unroll
      for (int r = 0; r < 4; ++r) {
        float v = hv[r];
        v = 0.5f * v * (1.0f + erff(v * 0.70710678118654752f));
        hb[r] = (__bf16)v;
      }
      *(bf16x4*)(h_t + (np * 16 + lr) * 136 + ko0) = hb;
    }
  }
  __syncthreads();

  // ---- proj2: [256 d] x [128 k] @ h^T -> stores, nothing after ----
  f32x4 acc2[4][4];
#pragma unroll
  for (int mtl = 0; mtl < 4; ++mtl)
#pragma unroll
    for (int np = 0; np < 4; ++np) acc2[mtl][np] = (f32x4){0.f, 0.f, 0.f, 0.f};
#pragma unroll
  for (int ksl = 0; ksl < 4; ++ksl) {
    bf16x8 bfr[4];
#pragma unroll
    for (int np = 0; np < 4; ++np)
      bfr[np] = *(const bf16x8*)(h_t + (np * 16 + lr) * 136 + ksl * 32 + kb * 8);
#pragma unroll
    for (int mtl = 0; mtl < 4; ++mtl) {
      int mtile = mtl * 4 + wv;
      bf16x8 af = *(const bf16x8*)(p2P + (((size_t)mtile * 4 + ksl) * 64 + lane) * 8);
#pragma unroll
      for (int np = 0; np < 4; ++np)
        acc2[mtl][np] = __builtin_amdgcn_mfma_f32_16x16x32_bf16(af, bfr[np], acc2[mtl][np], 0, 0, 0);
    }
  }
#pragma unroll
  for (int mtl = 0; mtl < 4; ++mtl) {
    int dcol0 = (mtl * 4 + wv) * 16 + kb * 4;
    f32x4 bias = *(const f32x4*)(proj2_b + dcol0);
#pragma unroll
    for (int np = 0; np < 4; ++np) {
      f32x4 v = acc2[mtl][np] + bias;
      *(f32x4*)(out_gbf + (pairbase + np * 16 + lr) * 256 + dcol0) = v;
    }
  }
}

extern "C" void kernel_launch(void* const* d_in, const int* in_sizes, int n_in,
                              void* d_out, int out_size, void* d_ws, size_t ws_size,
                              hipStream_t stream) {
  const float* positions = (const float*)d_in[0];
  const int* atomic_numbers = (const int*)d_in[1];
  const float* emb_z = (const float*)d_in[2];
  const float* electron_config = (const float*)d_in[3];
  const float* config_W = (const float*)d_in[4];
  const float* config_b = (const float*)d_in[5];
  const float* mult_W = (const float*)d_in[6];
  const float* charge_W = (const float*)d_in[7];
  const float* gbf_means = (const float*)d_in[8];
  const float* gbf_stds = (const float*)d_in[9];
  const float* gbf_mul = (const float*)d_in[10];
  const float* gbf_bias = (const float*)d_in[11];
  const float* proj1_W = (const float*)d_in[12];
  const float* proj1_b = (const float*)d_in[13];
  const float* proj2_W = (const float*)d_in[14];
  const float* proj2_b = (const float*)d_in[15];
  const float* dir_W = (const float*)d_in[16];
  const float* dir_b = (const float*)d_in[17];

  float* out = (float*)d_out;
  float* out_node = out;
  float* out_gbf = out + 262144;
  float* out_dir = out + 262144 + 67108864;

  char* ws = (char*)d_ws;
  __bf16* dirP = (__bf16*)(ws);
  __bf16* p1P = (__bf16*)(ws + 131072);
  __bf16* p2P = (__bf16*)(ws + 131072 + 32768);
  float* f_az = (float*)(ws + 229376);
  float* f_po = (float*)(ws + 229376 + 256);
  float* inv_std = (float*)(ws + 229376 + 512);
  float* coef = (float*)(ws + 229376 + 1024);

  prep_kernel<<<64, 256, 0, stream>>>(dir_W, proj1_W, proj2_W, gbf_stds, dirP, p1P,
                                      p2P, f_az, f_po, inv_std, coef);
  dir_kernel<<<4096, 256, 0, stream>>>(positions, dir_b, dirP, f_az, f_po, out_dir);
  gbf_kernel<<<4096, 256, 0, stream>>>(positions, atomic_numbers, gbf_means, gbf_mul,
                                       gbf_bias, proj1_b, proj2_b, p1P, p2P, inv_std,
                                       coef, out_gbf);
  node_kernel<<<1024, 256, 0, stream>>>(atomic_numbers, emb_z, electron_config,
                                        config_W, config_b, mult_W, charge_W, out_node);
}

// Round 5
// 160.696 us; speedup vs baseline: 1.0989x; 1.0989x over previous
//
#include <hip/hip_runtime.h>
#include <math.h>

typedef __bf16 bf16x8 __attribute__((ext_vector_type(8)));
typedef __bf16 bf16x4 __attribute__((ext_vector_type(4)));
typedef float f32x4 __attribute__((ext_vector_type(4)));

#define PI_D 3.14159265358979323846

// ---------------------------------------------------------------------------
// Prep: pack weights into MFMA-fragment-ordered bf16 (A-operand layout:
// within-tile idx = lane&15 on the output dim, k = (lane>>4)*8 + j).
// Packed flat: [((tile*KS + ks)*64 + l)*8 + j] -> wave reads contiguous 1KB.
// ---------------------------------------------------------------------------
__global__ void prep_kernel(const float* __restrict__ dir_W,
                            const float* __restrict__ proj1_W,
                            const float* __restrict__ proj2_W,
                            const float* __restrict__ gbf_stds,
                            __bf16* __restrict__ dirP, __bf16* __restrict__ p1P,
                            __bf16* __restrict__ p2P,
                            float* __restrict__ f_az, float* __restrict__ f_po,
                            float* __restrict__ inv_std, float* __restrict__ coef) {
  int tid = threadIdx.x + blockIdx.x * blockDim.x;
  int nth = gridDim.x * blockDim.x;
  // dir_W (256 x 256): 16 d-tiles, 8 ksteps
  for (int o = tid; o < 256 * 256; o += nth) {
    int j = o & 7, l = (o >> 3) & 63, ks = (o >> 9) & 7, nt = o >> 12;
    int d = nt * 16 + (l & 15);
    int s = ks * 32 + (l >> 4) * 8 + j;
    dirP[o] = (__bf16)dir_W[s * 256 + d];
  }
  // proj1_W (128 x 128): 8 ko-tiles, 4 ksteps
  for (int o = tid; o < 128 * 128; o += nth) {
    int j = o & 7, l = (o >> 3) & 63, ks = (o >> 9) & 3, nt = o >> 11;
    int ko = nt * 16 + (l & 15);
    int ki = ks * 32 + (l >> 4) * 8 + j;
    p1P[o] = (__bf16)proj1_W[ki * 128 + ko];
  }
  // proj2_W (128 x 256): 16 d-tiles, 4 ksteps
  for (int o = tid; o < 128 * 256; o += nth) {
    int j = o & 7, l = (o >> 3) & 63, ks = (o >> 9) & 3, nt = o >> 11;
    int d = nt * 16 + (l & 15);
    int k = ks * 32 + (l >> 4) * 8 + j;
    p2P[o] = (__bf16)proj2_W[k * 256 + d];
  }
  if (blockIdx.x == 0 && threadIdx.x < 64) {
    int q = threadIdx.x;
    double l0 = log(2.0 * 1e-4);
    double l1a = log(2.0 * 2.0 * PI_D);
    double l1p = log(2.0 * PI_D);
    double ta = l0 + (l1a - l0) * (double)q / 63.0;
    double tp = l0 + (l1p - l0) * (double)q / 63.0;
    f_az[q] = (float)(2.0 * PI_D / exp(ta));
    f_po[q] = (float)(2.0 * PI_D / exp(tp));
  }
  if (blockIdx.x == 1 && threadIdx.x < 128) {
    int k = threadIdx.x;
    float sd = fabsf(gbf_stds[k]) + 0.01f;
    inv_std[k] = 1.0f / sd;
    coef[k] = (float)(1.0 / (sqrt(2.0 * 3.14159) * (double)sd));
  }
}

// ---------------------------------------------------------------------------
// Node features: node = emb_z[z] + elec + mult_W[1] + charge_W[0]
// ---------------------------------------------------------------------------
__global__ void node_kernel(const int* __restrict__ an, const float* __restrict__ emb_z,
                            const float* __restrict__ ec, const float* __restrict__ cW,
                            const float* __restrict__ cb, const float* __restrict__ mult_W,
                            const float* __restrict__ charge_W, float* __restrict__ out_node) {
  int bi = blockIdx.x;  // b*256 + i
  int b = bi >> 8, i = bi & 255;
  int d = threadIdx.x;
  int z = (i == 0) ? 101 : an[b * 255 + i - 1];
  float elec = 0.0f;
  if (i != 0) {
    for (int f = 0; f < 20; ++f) elec += ec[z * 20 + f] * cW[f * 256 + d];
    elec += cb[d];
  }
  float v = emb_z[z * 256 + d] + elec + mult_W[256 + d] + charge_W[d];
  __builtin_nontemporal_store(v, &out_node[(size_t)bi * 256 + d]);
}

// ---------------------------------------------------------------------------
// Fused pair kernel: block = (b, i, 64 j's). 256 threads = 4 waves.
// Swapped-operand MFMAs: A = weights (output dim), B = activations (pairs)
// -> C lane holds 4 consecutive output cols -> f32x4 nontemporal stores
// (keeps packed weights L2-resident against the 512MB write stream).
// ---------------------------------------------------------------------------
__global__ __launch_bounds__(256, 4) void pair_kernel(
    const float* __restrict__ positions, const int* __restrict__ atomic_numbers,
    const float* __restrict__ gbf_means, const float* __restrict__ gbf_mul,
    const float* __restrict__ gbf_bias, const float* __restrict__ proj1_b,
    const float* __restrict__ proj2_b, const float* __restrict__ dir_b,
    const __bf16* __restrict__ dirP, const __bf16* __restrict__ p1P,
    const __bf16* __restrict__ p2P, const float* __restrict__ f_az,
    const float* __restrict__ f_po, const float* __restrict__ inv_stdv,
    const float* __restrict__ coefv, float* __restrict__ out_gbf,
    float* __restrict__ out_dir) {
  // one [64][136] bf16 buffer reused: az-half sinusoids, po-half, gauss, h
  __shared__ __align__(16) __bf16 buf[64 * 136];
  __shared__ float s_az[64], s_po[64], s_gx[64];

  const int tid = threadIdx.x;
  const int bid = blockIdx.x;
  const int jt = bid & 3;
  const int i = (bid >> 2) & 255;
  const int b = bid >> 10;
  const int j0 = jt * 64;
  const long pairbase = ((long)(b * 256 + i)) * 256 + j0;

  const int lane = tid & 63, wv = tid >> 6;
  const int lr = lane & 15, kb = lane >> 4;

  // ---- phase 0: per-pair scalars ----
  if (tid < 64) {
    int p = tid, j = j0 + p;
    float pxi = 0.f, pyi = 0.f, pzi = 0.f, pxj = 0.f, pyj = 0.f, pzj = 0.f;
    if (i != 0) { const float* q = positions + ((size_t)b * 255 + (i - 1)) * 3; pxi = q[0]; pyi = q[1]; pzi = q[2]; }
    if (j != 0) { const float* q = positions + ((size_t)b * 255 + (j - 1)) * 3; pxj = q[0]; pyj = q[1]; pzj = q[2]; }
    float dx = pxj - pxi, dy = pyj - pyi, dz = pzj - pzi;
    float sq = dx * dx + dy * dy + dz * dz;
    float dist = sqrtf(sq + 1e-12f);
    float inv = 1.0f / (dist + 1e-5f);
    float ndx = dx * inv, ndy = dy * inv, ndz = dz * inv;
    bool diag = (i == j);
    float xs = diag ? 1.0f : ndx;
    float ys = diag ? 0.0f : ndy;
    s_az[p] = atan2f(ys, xs);
    float cz = fminf(fmaxf(ndz, -1.0f + 1e-6f), 1.0f - 1e-6f);
    s_po[p] = acosf(cz);
    int zi = (i == 0) ? 101 : atomic_numbers[b * 255 + i - 1];
    int zj = ((j == 0) ? 101 : atomic_numbers[b * 255 + j - 1]) + 128;
    float mul = gbf_mul[zi] + gbf_mul[zj];
    float bia = gbf_bias[zi] + gbf_bias[zj];
    s_gx[p] = mul * dist + bia;
  }
  __syncthreads();

  // ---- dir GEMM over two K-halves (az: k 0..127, po: k 128..255) ----
  f32x4 acc[4][4];
#pragma unroll
  for (int mtl = 0; mtl < 4; ++mtl)
#pragma unroll
    for (int np = 0; np < 4; ++np) acc[mtl][np] = (f32x4){0.f, 0.f, 0.f, 0.f};

  for (int half = 0; half < 2; ++half) {
    // stage this half's sinusoids: row p pitch 136: [sin 64 | cos 64]
#pragma unroll
    for (int it = 0; it < 2; ++it) {
      int job = tid + it * 256;  // 0..511 = 64 p * 8 groups
      int p = job >> 3, g = job & 7;
      int q0 = g * 8;
      float ang = half ? s_po[p] : s_az[p];
      const float* ft = half ? f_po : f_az;
      bf16x8 sv, cv;
#pragma unroll
      for (int t = 0; t < 8; ++t) {
        float ph = ang * ft[q0 + t];  // f32 product, same as reference
        double r = (double)ph * 0.15915494309189535;  // /(2*pi) -> revolutions
        double fr = r - rint(r);                      // exact reduction
        float frf = (float)fr;
        sv[t] = (__bf16)__builtin_amdgcn_sinf(frf);   // sin(2*pi*x)
        cv[t] = (__bf16)__builtin_amdgcn_cosf(frf);
      }
      *(bf16x8*)(buf + p * 136 + q0) = sv;
      *(bf16x8*)(buf + p * 136 + 64 + q0) = cv;
    }
    __syncthreads();
#pragma unroll
    for (int ksl = 0; ksl < 4; ++ksl) {
      int ks = half * 4 + ksl;
      bf16x8 bfr[4];
#pragma unroll
      for (int np = 0; np < 4; ++np)
        bfr[np] = *(const bf16x8*)(buf + (np * 16 + lr) * 136 + ksl * 32 + kb * 8);
#pragma unroll
      for (int mtl = 0; mtl < 4; ++mtl) {
        int mtile = mtl * 4 + wv;
        bf16x8 af = *(const bf16x8*)(dirP + (((size_t)mtile * 8 + ks) * 64 + lane) * 8);
#pragma unroll
        for (int np = 0; np < 4; ++np)
          acc[mtl][np] = __builtin_amdgcn_mfma_f32_16x16x32_bf16(af, bfr[np], acc[mtl][np], 0, 0, 0);
      }
    }
    __syncthreads();  // half0: buf restage fence; half1: gauss overwrite fence
  }

  // ---- dir epilogue: nontemporal f32x4 stores ----
#pragma unroll
  for (int mtl = 0; mtl < 4; ++mtl) {
    int dcol0 = (mtl * 4 + wv) * 16 + kb * 4;
    f32x4 bias = *(const f32x4*)(dir_b + dcol0);
#pragma unroll
    for (int np = 0; np < 4; ++np) {
      f32x4 v = acc[mtl][np] + bias;
      __builtin_nontemporal_store(v, (f32x4*)(out_dir + (pairbase + np * 16 + lr) * 256 + dcol0));
    }
  }

  // ---- gauss stage -> buf ----
#pragma unroll
  for (int it = 0; it < 4; ++it) {
    int job = tid + it * 256;  // 64 p * 16 groups
    int p = job >> 4, g = job & 15;
    int k0 = g * 8;
    float gx = s_gx[p];
    bf16x8 gv;
#pragma unroll
    for (int t = 0; t < 8; ++t) {
      int k = k0 + t;
      float x = (gx - gbf_means[k]) * inv_stdv[k];
      gv[t] = (__bf16)(exp2f(-0.72134752044448170f * x * x) * coefv[k]);
    }
    *(bf16x8*)(buf + p * 136 + k0) = gv;
  }
  __syncthreads();

  // ---- proj1: [128 ko] x [128 k] @ gauss^T ----
  f32x4 acc1[2][4];
#pragma unroll
  for (int mtl = 0; mtl < 2; ++mtl)
#pragma unroll
    for (int np = 0; np < 4; ++np) acc1[mtl][np] = (f32x4){0.f, 0.f, 0.f, 0.f};
#pragma unroll
  for (int ksl = 0; ksl < 4; ++ksl) {
    bf16x8 bfr[4];
#pragma unroll
    for (int np = 0; np < 4; ++np)
      bfr[np] = *(const bf16x8*)(buf + (np * 16 + lr) * 136 + ksl * 32 + kb * 8);
#pragma unroll
    for (int mtl = 0; mtl < 2; ++mtl) {
      int mtile = mtl * 4 + wv;  // 0..7
      bf16x8 af = *(const bf16x8*)(p1P + (((size_t)mtile * 4 + ksl) * 64 + lane) * 8);
#pragma unroll
      for (int np = 0; np < 4; ++np)
        acc1[mtl][np] = __builtin_amdgcn_mfma_f32_16x16x32_bf16(af, bfr[np], acc1[mtl][np], 0, 0, 0);
    }
  }
  __syncthreads();  // gauss fully consumed before h overwrites buf

  // ---- GELU -> h into buf (8B ds_writes) ----
#pragma unroll
  for (int mtl = 0; mtl < 2; ++mtl) {
    int ko0 = (mtl * 4 + wv) * 16 + kb * 4;
    f32x4 pb = *(const f32x4*)(proj1_b + ko0);
#pragma unroll
    for (int np = 0; np < 4; ++np) {
      f32x4 hv = acc1[mtl][np] + pb;
      bf16x4 hb;
#pragma unroll
      for (int r = 0; r < 4; ++r) {
        float v = hv[r];
        v = 0.5f * v * (1.0f + erff(v * 0.70710678118654752f));
        hb[r] = (__bf16)v;
      }
      *(bf16x4*)(buf + (np * 16 + lr) * 136 + ko0) = hb;
    }
  }
  __syncthreads();

  // ---- proj2: [256 d] x [128 k] @ h^T ----
  f32x4 acc2[4][4];
#pragma unroll
  for (int mtl = 0; mtl < 4; ++mtl)
#pragma unroll
    for (int np = 0; np < 4; ++np) acc2[mtl][np] = (f32x4){0.f, 0.f, 0.f, 0.f};
#pragma unroll
  for (int ksl = 0; ksl < 4; ++ksl) {
    bf16x8 bfr[4];
#pragma unroll
    for (int np = 0; np < 4; ++np)
      bfr[np] = *(const bf16x8*)(buf + (np * 16 + lr) * 136 + ksl * 32 + kb * 8);
#pragma unroll
    for (int mtl = 0; mtl < 4; ++mtl) {
      int mtile = mtl * 4 + wv;
      bf16x8 af = *(const bf16x8*)(p2P + (((size_t)mtile * 4 + ksl) * 64 + lane) * 8);
#pragma unroll
      for (int np = 0; np < 4; ++np)
        acc2[mtl][np] = __builtin_amdgcn_mfma_f32_16x16x32_bf16(af, bfr[np], acc2[mtl][np], 0, 0, 0);
    }
  }
  // ---- gbf epilogue: nontemporal f32x4 stores ----
#pragma unroll
  for (int mtl = 0; mtl < 4; ++mtl) {
    int dcol0 = (mtl * 4 + wv) * 16 + kb * 4;
    f32x4 bias = *(const f32x4*)(proj2_b + dcol0);
#pragma unroll
    for (int np = 0; np < 4; ++np) {
      f32x4 v = acc2[mtl][np] + bias;
      __builtin_nontemporal_store(v, (f32x4*)(out_gbf + (pairbase + np * 16 + lr) * 256 + dcol0));
    }
  }
}

extern "C" void kernel_launch(void* const* d_in, const int* in_sizes, int n_in,
                              void* d_out, int out_size, void* d_ws, size_t ws_size,
                              hipStream_t stream) {
  const float* positions = (const float*)d_in[0];
  const int* atomic_numbers = (const int*)d_in[1];
  const float* emb_z = (const float*)d_in[2];
  const float* electron_config = (const float*)d_in[3];
  const float* config_W = (const float*)d_in[4];
  const float* config_b = (const float*)d_in[5];
  const float* mult_W = (const float*)d_in[6];
  const float* charge_W = (const float*)d_in[7];
  const float* gbf_means = (const float*)d_in[8];
  const float* gbf_stds = (const float*)d_in[9];
  const float* gbf_mul = (const float*)d_in[10];
  const float* gbf_bias = (const float*)d_in[11];
  const float* proj1_W = (const float*)d_in[12];
  const float* proj1_b = (const float*)d_in[13];
  const float* proj2_W = (const float*)d_in[14];
  const float* proj2_b = (const float*)d_in[15];
  const float* dir_W = (const float*)d_in[16];
  const float* dir_b = (const float*)d_in[17];

  float* out = (float*)d_out;
  float* out_node = out;
  float* out_gbf = out + 262144;
  float* out_dir = out + 262144 + 67108864;

  char* ws = (char*)d_ws;
  __bf16* dirP = (__bf16*)(ws);
  __bf16* p1P = (__bf16*)(ws + 131072);
  __bf16* p2P = (__bf16*)(ws + 131072 + 32768);
  float* f_az = (float*)(ws + 229376);
  float* f_po = (float*)(ws + 229376 + 256);
  float* inv_std = (float*)(ws + 229376 + 512);
  float* coef = (float*)(ws + 229376 + 1024);

  prep_kernel<<<64, 256, 0, stream>>>(dir_W, proj1_W, proj2_W, gbf_stds, dirP, p1P,
                                      p2P, f_az, f_po, inv_std, coef);
  node_kernel<<<1024, 256, 0, stream>>>(atomic_numbers, emb_z, electron_config,
                                        config_W, config_b, mult_W, charge_W, out_node);
  pair_kernel<<<4096, 256, 0, stream>>>(positions, atomic_numbers, gbf_means, gbf_mul,
                                        gbf_bias, proj1_b, proj2_b, dir_b, dirP, p1P,
                                        p2P, f_az, f_po, inv_std, coef, out_gbf, out_dir);
}